// Round 2
// baseline (821.789 us; speedup 1.0000x reference)
//
#include <hip/hip_runtime.h>
#include <hip/hip_bf16.h>

namespace {

constexpr int kCin   = 128;
constexpr int kHW    = 12544;   // 112*112
constexpr int kW     = 112;
constexpr int kGrps  = 49;      // output kernel: 49 blocks * 256 tokens per image
constexpr int kTiles = 196;     // main kernel: 196 blocks * 64 tokens per image
constexpr size_t kOut1Off = (size_t)16 * 128 * kHW;  // element offset of assignment map

__device__ __forceinline__ float bf2f(unsigned short u) {
  union { unsigned int i; float f; } v;
  v.i = ((unsigned int)u) << 16;
  return v.f;
}

__device__ __forceinline__ unsigned short f2bf(float f) {
  union { float f; unsigned int i; } v;
  v.f = f;
  unsigned int x = v.i;
  x += 0x7fffu + ((x >> 16) & 1u);   // RNE
  return (unsigned short)(x >> 16);
}

// ---- dtype-templated load/store helpers (BF=true: bf16, else fp32) ----
template <bool BF>
__device__ __forceinline__ float ld1(const void* p, size_t i) {
  if constexpr (BF) return bf2f(((const unsigned short*)p)[i]);
  else              return ((const float*)p)[i];
}
template <bool BF>
__device__ __forceinline__ void ld4(const void* p, size_t i, float o[4]) {
  if constexpr (BF) {
    const ushort4 u = *reinterpret_cast<const ushort4*>((const unsigned short*)p + i);
    o[0] = bf2f(u.x); o[1] = bf2f(u.y); o[2] = bf2f(u.z); o[3] = bf2f(u.w);
  } else {
    const float4 u = *reinterpret_cast<const float4*>((const float*)p + i);
    o[0] = u.x; o[1] = u.y; o[2] = u.z; o[3] = u.w;
  }
}
template <bool BF>
__device__ __forceinline__ void st1(void* p, size_t i, float v) {
  if constexpr (BF) ((unsigned short*)p)[i] = f2bf(v);
  else              ((float*)p)[i] = v;
}

// ---------------------------------------------------------------------------
// Kernel 0: detect input dtype. bf16 f_w values are ~N(0, 0.09): none exceed 4.
// fp32 f_w read as bf16 pairs: ~25% of ushorts are mantissa garbage with
// uniform-random exponent -> |v|>4 for ~half of those. flag=1 means bf16.
// ---------------------------------------------------------------------------
__global__ void detect_dtype(const unsigned short* __restrict__ fw, int* __restrict__ flag) {
  __shared__ int cnt_s;
  if (threadIdx.x == 0) cnt_s = 0;
  __syncthreads();
  int c = 0;
  for (int i = threadIdx.x; i < 4096; i += 256) {
    const float v = bf2f(fw[i]);
    if (fabsf(v) > 4.0f) ++c;
  }
  atomicAdd(&cnt_s, c);
  __syncthreads();
  if (threadIdx.x == 0) flag[0] = (cnt_s > 100) ? 0 : 1;
}

// ---------------------------------------------------------------------------
// Kernel 1: ONE 64-token tile per block (grid 16*196=3136 -> 12.25 blocks/CU
// of work, 6 resident via 26.7KB LDS -> ~75% occupancy for latency hiding;
// the previous 784-block version sat at 27% occupancy, 30% VALUBusy,
// stall-bound). Per tile: f,v = convs (192x64 GEMM in registers), per-token
// head-wise cosine sim vs centers + sigmoid + argmax, block reduction,
// atomics into global accumulators. (s, idx) staged into d_out ch 0..7.
// ---------------------------------------------------------------------------
struct SMain {
  float fh[96 * 65];            // f rows (phase B1), then reused for v rows (B2)
  float cn[4][24];
  float s[4][64];
  unsigned char idx[4][64];
  unsigned char q[64];
};

template <bool BF>
__device__ __forceinline__ void main_body(
    SMain& sm,
    const void* __restrict__ x,  const void* __restrict__ f_w, const void* __restrict__ f_b,
    const void* __restrict__ v_w, const void* __restrict__ v_b,
    const void* __restrict__ sim_alpha, const void* __restrict__ sim_beta,
    const void* __restrict__ centers,
    void* __restrict__ out0,
    float* __restrict__ aggsum, float* __restrict__ vpool, float* __restrict__ cnt)
{
  const int tid  = threadIdx.x;
  const int b    = blockIdx.x / kTiles;
  const int tile = blockIdx.x % kTiles;
  const int hw0  = tile * 64;

  if (tid < 4) {
    float cv[24];
    float n2 = 0.f;
#pragma unroll
    for (int c = 0; c < 24; ++c) { cv[c] = ld1<BF>(centers, tid * 24 + c); n2 += cv[c] * cv[c]; }
    const float inv = 1.f / fmaxf(sqrtf(n2), 1e-12f);
#pragma unroll
    for (int c = 0; c < 24; ++c) sm.cn[tid][c] = cv[c] * inv;
  }
  const float alpha = ld1<BF>(sim_alpha, 0);
  const float beta  = ld1<BF>(sim_beta, 0);

  // GEMM mapping: 16x16 threads; rows ty*12..+11, cols tx*4..+3 (ty wave-uniform f/v)
  const int ty = tid >> 4;
  const int tx = tid & 15;
  const bool is_f = (ty < 8);
  const void*  wsel  = is_f ? f_w : v_w;
  const void*  bsel  = is_f ? f_b : v_b;
  const size_t wrow0 = (size_t)(is_f ? ty * 12 : ty * 12 - 96);
  float bias[12];
#pragma unroll
  for (int r = 0; r < 12; ++r) bias[r] = ld1<BF>(bsel, wrow0 + r);

  const int e   = tid >> 6;
  const int tok = tid & 63;

  __syncthreads();

  // ---- phase A: [f;v](192) x tokens(64), acc in registers ----
  float acc[12][4];
#pragma unroll
  for (int r = 0; r < 12; ++r)
#pragma unroll
    for (int j = 0; j < 4; ++j) acc[r][j] = 0.f;

  const size_t xbase = ((size_t)b * kCin) * kHW + hw0 + tx * 4;
  for (int i = 0; i < 128; i += 4) {
    float xv[4][4];
#pragma unroll
    for (int ci = 0; ci < 4; ++ci) ld4<BF>(x, xbase + (size_t)(i + ci) * kHW, xv[ci]);
    // weight rows in 2 chunks of 6 to keep live VGPRs under the 85 cap (6 waves/SIMD)
    float wv[6][4];
#pragma unroll
    for (int r = 0; r < 6; ++r) ld4<BF>(wsel, (wrow0 + r) * 128 + i, wv[r]);
#pragma unroll
    for (int r = 0; r < 6; ++r)
#pragma unroll
      for (int ci = 0; ci < 4; ++ci)
#pragma unroll
        for (int j = 0; j < 4; ++j)
          acc[r][j] = fmaf(wv[r][ci], xv[ci][j], acc[r][j]);
#pragma unroll
    for (int r = 0; r < 6; ++r) ld4<BF>(wsel, (wrow0 + 6 + r) * 128 + i, wv[r]);
#pragma unroll
    for (int r = 0; r < 6; ++r)
#pragma unroll
      for (int ci = 0; ci < 4; ++ci)
#pragma unroll
        for (int j = 0; j < 4; ++j)
          acc[6 + r][j] = fmaf(wv[r][ci], xv[ci][j], acc[6 + r][j]);
  }

  // ---- write f half only; v half stays in registers through B1 ----
  if (is_f) {
#pragma unroll
    for (int r = 0; r < 12; ++r)
#pragma unroll
      for (int j = 0; j < 4; ++j)
        sm.fh[(ty * 12 + r) * 65 + tx * 4 + j] = acc[r][j] + bias[r];
  }
  __syncthreads();

  // ---- phase B1: sim / sigmoid / argmax, stage (s, idx) into d_out ch 0..7 ----
  {
    float dm[4] = {0.f, 0.f, 0.f, 0.f};
    float n2 = 0.f;
#pragma unroll
    for (int c = 0; c < 24; ++c) {
      const float fc = sm.fh[(e * 24 + c) * 65 + tok];
      n2 += fc * fc;
      dm[0] += fc * sm.cn[0][c];
      dm[1] += fc * sm.cn[1][c];
      dm[2] += fc * sm.cn[2][c];
      dm[3] += fc * sm.cn[3][c];
    }
    const float inv = 1.f / fmaxf(sqrtf(n2), 1e-12f);
    float s[4];
#pragma unroll
    for (int m = 0; m < 4; ++m) {
      const float z = beta + alpha * dm[m] * inv;
      s[m] = 1.f / (1.f + __expf(-z));
    }
    float best = -1.f;
    int bi = 0;
#pragma unroll
    for (int m = 0; m < 4; ++m)
      if (s[m] > best) { best = s[m]; bi = m; }   // strict >: first max, like jnp.argmax

    const int hw = hw0 + tok;
    st1<BF>(out0, ((size_t)(b * 128 + e)) * kHW + hw, best);          // stage s
    st1<BF>(out0, ((size_t)(b * 128 + 4 + e)) * kHW + hw, (float)bi); // stage idx
    sm.s[e][tok]   = best;
    sm.idx[e][tok] = (unsigned char)bi;
    if (e == 0) {
      const int h = hw / kW;
      const int w = hw - h * kW;
      sm.q[tok] = (unsigned char)((h >= 56 ? 2 : 0) + (w >= 56 ? 1 : 0));
    }
  }
  __syncthreads();

  // ---- overwrite LDS with v half (from registers) ----
  if (!is_f) {
#pragma unroll
    for (int r = 0; r < 12; ++r)
#pragma unroll
      for (int j = 0; j < 4; ++j)
        sm.fh[((ty - 8) * 12 + r) * 65 + tx * 4 + j] = acc[r][j] + bias[r];
  }
  __syncthreads();

  // ---- phase B2: block reduction over 64 tokens, 2 token-halves in parallel ----
  float agg_m[4]  = {0.f, 0.f, 0.f, 0.f};
  float pool_q[4] = {0.f, 0.f, 0.f, 0.f};
  float cacc = 0.f;
  if (tid < 192) {
    const int half = tid / 96;
    const int c    = tid - half * 96;
    const int eh   = c / 24;
    const int row0 = c * 65;
    const int t20  = half * 32;
    for (int k = 0; k < 32; ++k) {
      const int t2 = t20 + k;
      const float v = sm.fh[row0 + t2];
      const float s = sm.s[eh][t2];
      const int  mi = sm.idx[eh][t2];
      const int  q  = sm.q[t2];
      const float sv = s * v;
      agg_m[0]  += (mi == 0) ? sv : 0.f;
      agg_m[1]  += (mi == 1) ? sv : 0.f;
      agg_m[2]  += (mi == 2) ? sv : 0.f;
      agg_m[3]  += (mi == 3) ? sv : 0.f;
      pool_q[0] += (q == 0) ? v : 0.f;
      pool_q[1] += (q == 1) ? v : 0.f;
      pool_q[2] += (q == 2) ? v : 0.f;
      pool_q[3] += (q == 3) ? v : 0.f;
    }
    const int eh2 = c / 24;
    const int cc  = c % 24;
    const int bh  = b * 4 + eh2;
#pragma unroll
    for (int m = 0; m < 4; ++m) {
      atomicAdd(&aggsum[(bh * 4 + m) * 24 + cc], agg_m[m]);
      atomicAdd(&vpool[(bh * 4 + m) * 24 + cc], pool_q[m]);
    }
  } else if (tid < 224) {
    const int p  = tid - 192;
    const int em = p >> 1;
    const int ce = em >> 2, cm = em & 3;
    const int t20 = (p & 1) * 32;
    for (int k = 0; k < 32; ++k) {
      const int t2 = t20 + k;
      cacc += (sm.idx[ce][t2] == cm) ? sm.s[ce][t2] : 0.f;
    }
    atomicAdd(&cnt[b * 16 + em], cacc);
  }
}

__global__ __launch_bounds__(256, 6) void cluster_main(
    const int* __restrict__ flag,
    const void* x, const void* f_w, const void* f_b, const void* v_w, const void* v_b,
    const void* sim_alpha, const void* sim_beta, const void* centers,
    void* out0, float* aggsum, float* vpool, float* cnt)
{
  __shared__ SMain sm;
  if (*flag)
    main_body<true>(sm, x, f_w, f_b, v_w, v_b, sim_alpha, sim_beta, centers, out0, aggsum, vpool, cnt);
  else
    main_body<false>(sm, x, f_w, f_b, v_w, v_b, sim_alpha, sim_beta, centers, out0, aggsum, vpool, cnt);
}

// ---------------------------------------------------------------------------
// Kernel 2: finalize + proto-projection table.
//   aggf[em][c] = (aggsum + vpool/3136) / (cnt + 1)      (in LDS)
//   ptab[b][o*16 + e*4 + m] = sum_c proj_w[o][e*24+c] * aggf[e][m][c]
// Since s commutes with the c-sum, the per-token combine+proj GEMM collapses
// to 4 scaled lookups of ptab columns (kernel 3).
// ---------------------------------------------------------------------------
template <bool BF>
__device__ __forceinline__ void ptab_body(
    float* __restrict__ af, const void* __restrict__ proj_w,
    const float* __restrict__ aggsum, const float* __restrict__ vpool,
    const float* __restrict__ cnt, float* __restrict__ ptab)
{
  const int b   = blockIdx.x;
  const int tid = threadIdx.x;
  for (int k = tid; k < 384; k += 256) {
    const int em = k / 24;
    af[k] = (aggsum[b * 384 + k] + vpool[b * 384 + k] * (1.f / 3136.f)) / (cnt[b * 16 + em] + 1.f);
  }
  __syncthreads();
#pragma unroll
  for (int i = 0; i < 8; ++i) {
    const int g  = i * 256 + tid;      // g = o*16 + em
    const int o  = g >> 4;
    const int em = g & 15;
    const int e  = em >> 2;
    float acc = 0.f;
#pragma unroll
    for (int c = 0; c < 24; ++c)
      acc = fmaf(ld1<BF>(proj_w, (size_t)o * 96 + e * 24 + c), af[em * 24 + c], acc);
    ptab[b * 2048 + g] = acc;
  }
}

__global__ void cluster_ptab(const int* __restrict__ flag, const void* proj_w,
                             const float* __restrict__ aggsum, const float* __restrict__ vpool,
                             const float* __restrict__ cnt, float* __restrict__ ptab) {
  __shared__ float af[384];
  if (*flag) ptab_body<true>(af, proj_w, aggsum, vpool, cnt, ptab);
  else       ptab_body<false>(af, proj_w, aggsum, vpool, cnt, ptab);
}

// ---------------------------------------------------------------------------
// Kernel 3: out[o][token] = proj_b[o] + sum_e s_e(token) * ptab[b][o][e][idx_e]
// Memory-bound: ~103 MB write. Also emits the assignment map for b=0 (raw
// copy of the staged idx register BEFORE the channel writes overwrite it).
// ---------------------------------------------------------------------------
struct SOut {
  float p[2048];   // [o][e*4+m] layout: conflict-free (m spreads banks)
  float pb[128];
};

template <bool BF>
__device__ __forceinline__ void out_body(
    SOut& so, const float* __restrict__ ptab,
    const void* __restrict__ proj_b, void* __restrict__ out0)
{
  const int tid = threadIdx.x;
  const int b   = blockIdx.x / kGrps;
  const int grp = blockIdx.x % kGrps;
  const int hw  = grp * 256 + tid;

  for (int k = tid; k < 2048; k += 256) so.p[k] = ptab[b * 2048 + k];
  if (tid < 128) so.pb[tid] = ld1<BF>(proj_b, tid);
  __syncthreads();

  const size_t base = ((size_t)(b * 128)) * kHW + hw;
  float sv[4];
  int   mi[4];
  float iv0 = 0.f;
#pragma unroll
  for (int e = 0; e < 4; ++e) {
    sv[e] = ld1<BF>(out0, base + (size_t)e * kHW);
    const float iv = ld1<BF>(out0, base + (size_t)(4 + e) * kHW);
    if (e == 0) iv0 = iv;
    mi[e] = (int)(iv + 0.5f);
  }
  if (b == 0) {
    // assignment map: head-0 idx of batch 0 (exact small-int in both dtypes)
    st1<BF>(out0, kOut1Off + hw, iv0);
  }

#pragma unroll 4
  for (int o = 0; o < 128; ++o) {
    float a = so.pb[o];
    a = fmaf(sv[0], so.p[o * 16 +  0 + mi[0]], a);
    a = fmaf(sv[1], so.p[o * 16 +  4 + mi[1]], a);
    a = fmaf(sv[2], so.p[o * 16 +  8 + mi[2]], a);
    a = fmaf(sv[3], so.p[o * 16 + 12 + mi[3]], a);
    st1<BF>(out0, base + (size_t)o * kHW, a);
  }
}

__global__ __launch_bounds__(256) void cluster_out(
    const int* __restrict__ flag,
    const void* proj_b, const float* __restrict__ ptab, void* out0)
{
  __shared__ SOut so;
  if (*flag) out_body<true>(so, ptab, proj_b, out0);
  else       out_body<false>(so, ptab, proj_b, out0);
}

}  // namespace

extern "C" void kernel_launch(void* const* d_in, const int* in_sizes, int n_in,
                              void* d_out, int out_size, void* d_ws, size_t ws_size,
                              hipStream_t stream) {
  const void* x         = d_in[0];
  const void* f_w       = d_in[1];
  const void* f_b       = d_in[2];
  const void* v_w       = d_in[3];
  const void* v_b       = d_in[4];
  const void* proj_w    = d_in[5];
  const void* proj_b    = d_in[6];
  const void* sim_alpha = d_in[7];
  const void* sim_beta  = d_in[8];
  const void* centers   = d_in[9];

  // ws layout: [0..15] bytes: dtype flag (int). Then floats:
  //   aggsum[6144] vpool[6144] cnt[256] ptab[32768]  -> ~177 KB total
  int*   flag   = (int*)d_ws;
  float* fws    = (float*)((char*)d_ws + 16);
  float* aggsum = fws;
  float* vpool  = fws + 6144;
  float* cnt    = fws + 12288;
  float* ptab   = fws + 12544;

  // zero flag + accumulators (ws is poisoned 0xAA before every call);
  // ptab is fully overwritten, no zeroing needed.
  hipMemsetAsync(d_ws, 0, 16 + 12544 * sizeof(float), stream);

  detect_dtype<<<dim3(1), dim3(256), 0, stream>>>((const unsigned short*)f_w, flag);
  cluster_main<<<dim3(16 * kTiles), dim3(256), 0, stream>>>(
      flag, x, f_w, f_b, v_w, v_b, sim_alpha, sim_beta, centers,
      d_out, aggsum, vpool, cnt);
  cluster_ptab<<<dim3(16), dim3(256), 0, stream>>>(flag, proj_w, aggsum, vpool, cnt, ptab);
  cluster_out<<<dim3(16 * kGrps), dim3(256), 0, stream>>>(flag, proj_b, ptab, d_out);
}

// Round 3
// 493.414 us; speedup vs baseline: 1.6655x; 1.6655x over previous
//
#include <hip/hip_runtime.h>
#include <hip/hip_bf16.h>

namespace {

constexpr int kCin   = 128;
constexpr int kHW    = 12544;   // 112*112
constexpr int kW     = 112;
constexpr int kGrps  = 49;      // output kernel: 49 blocks * 256 tokens per image
constexpr int kTiles = 196;     // main kernel: 196 blocks * 64 tokens per image
constexpr size_t kOut1Off = (size_t)16 * 128 * kHW;  // element offset of assignment map

__device__ __forceinline__ float bf2f(unsigned short u) {
  union { unsigned int i; float f; } v;
  v.i = ((unsigned int)u) << 16;
  return v.f;
}

__device__ __forceinline__ unsigned short f2bf(float f) {
  union { float f; unsigned int i; } v;
  v.f = f;
  unsigned int x = v.i;
  x += 0x7fffu + ((x >> 16) & 1u);   // RNE
  return (unsigned short)(x >> 16);
}

// ---- dtype-templated load/store helpers (BF=true: bf16, else fp32) ----
template <bool BF>
__device__ __forceinline__ float ld1(const void* p, size_t i) {
  if constexpr (BF) return bf2f(((const unsigned short*)p)[i]);
  else              return ((const float*)p)[i];
}
template <bool BF>
__device__ __forceinline__ void ld4(const void* p, size_t i, float o[4]) {
  if constexpr (BF) {
    const ushort4 u = *reinterpret_cast<const ushort4*>((const unsigned short*)p + i);
    o[0] = bf2f(u.x); o[1] = bf2f(u.y); o[2] = bf2f(u.z); o[3] = bf2f(u.w);
  } else {
    const float4 u = *reinterpret_cast<const float4*>((const float*)p + i);
    o[0] = u.x; o[1] = u.y; o[2] = u.z; o[3] = u.w;
  }
}
template <bool BF>
__device__ __forceinline__ void st1(void* p, size_t i, float v) {
  if constexpr (BF) ((unsigned short*)p)[i] = f2bf(v);
  else              ((float*)p)[i] = v;
}

// ---------------------------------------------------------------------------
// Kernel 0: detect input dtype. bf16 f_w values are ~N(0, 0.09): none exceed 4.
// fp32 f_w read as bf16 pairs: ~25% of ushorts are mantissa garbage with
// uniform-random exponent -> |v|>4 for ~half of those. flag=1 means bf16.
// ---------------------------------------------------------------------------
__global__ void detect_dtype(const unsigned short* __restrict__ fw, int* __restrict__ flag) {
  __shared__ int cnt_s;
  if (threadIdx.x == 0) cnt_s = 0;
  __syncthreads();
  int c = 0;
  for (int i = threadIdx.x; i < 4096; i += 256) {
    const float v = bf2f(fw[i]);
    if (fabsf(v) > 4.0f) ++c;
  }
  atomicAdd(&cnt_s, c);
  __syncthreads();
  if (threadIdx.x == 0) flag[0] = (cnt_s > 100) ? 0 : 1;
}

// ---------------------------------------------------------------------------
// Kernel 1: ONE 64-token tile per block (grid 16*196=3136 -> 12.25 blocks/CU
// of work). LDS 26.7KB -> 6 blocks/CU resident. __launch_bounds__(256,4):
// NOT (256,6) — that capped the allocator below phase A's ~95-reg live set,
// spilled acc to scratch (VGPR 40, WRITE_SIZE 810MB, 2x slower). With min=4
// the compiler lands at 64 VGPR (8 blocks/CU by regs), so residency is
// LDS-limited at 6 with zero spill.
// ---------------------------------------------------------------------------
struct SMain {
  float fh[96 * 65];            // f rows (phase B1), then reused for v rows (B2)
  float cn[4][24];
  float s[4][64];
  unsigned char idx[4][64];
  unsigned char q[64];
};

template <bool BF>
__device__ __forceinline__ void main_body(
    SMain& sm,
    const void* __restrict__ x,  const void* __restrict__ f_w, const void* __restrict__ f_b,
    const void* __restrict__ v_w, const void* __restrict__ v_b,
    const void* __restrict__ sim_alpha, const void* __restrict__ sim_beta,
    const void* __restrict__ centers,
    void* __restrict__ out0,
    float* __restrict__ aggsum, float* __restrict__ vpool, float* __restrict__ cnt)
{
  const int tid  = threadIdx.x;
  const int b    = blockIdx.x / kTiles;
  const int tile = blockIdx.x % kTiles;
  const int hw0  = tile * 64;

  if (tid < 4) {
    float cv[24];
    float n2 = 0.f;
#pragma unroll
    for (int c = 0; c < 24; ++c) { cv[c] = ld1<BF>(centers, tid * 24 + c); n2 += cv[c] * cv[c]; }
    const float inv = 1.f / fmaxf(sqrtf(n2), 1e-12f);
#pragma unroll
    for (int c = 0; c < 24; ++c) sm.cn[tid][c] = cv[c] * inv;
  }
  const float alpha = ld1<BF>(sim_alpha, 0);
  const float beta  = ld1<BF>(sim_beta, 0);

  // GEMM mapping: 16x16 threads; rows ty*12..+11, cols tx*4..+3 (ty wave-uniform f/v)
  const int ty = tid >> 4;
  const int tx = tid & 15;
  const bool is_f = (ty < 8);
  const void*  wsel  = is_f ? f_w : v_w;
  const void*  bsel  = is_f ? f_b : v_b;
  const size_t wrow0 = (size_t)(is_f ? ty * 12 : ty * 12 - 96);
  float bias[12];
#pragma unroll
  for (int r = 0; r < 12; ++r) bias[r] = ld1<BF>(bsel, wrow0 + r);

  const int e   = tid >> 6;
  const int tok = tid & 63;

  __syncthreads();

  // ---- phase A: [f;v](192) x tokens(64), acc in registers ----
  float acc[12][4];
#pragma unroll
  for (int r = 0; r < 12; ++r)
#pragma unroll
    for (int j = 0; j < 4; ++j) acc[r][j] = 0.f;

  const size_t xbase = ((size_t)b * kCin) * kHW + hw0 + tx * 4;
  for (int i = 0; i < 128; i += 4) {
    float xv[4][4];
#pragma unroll
    for (int ci = 0; ci < 4; ++ci) ld4<BF>(x, xbase + (size_t)(i + ci) * kHW, xv[ci]);
    // weight rows in 2 chunks of 6 to bound the live set
    float wv[6][4];
#pragma unroll
    for (int r = 0; r < 6; ++r) ld4<BF>(wsel, (wrow0 + r) * 128 + i, wv[r]);
#pragma unroll
    for (int r = 0; r < 6; ++r)
#pragma unroll
      for (int ci = 0; ci < 4; ++ci)
#pragma unroll
        for (int j = 0; j < 4; ++j)
          acc[r][j] = fmaf(wv[r][ci], xv[ci][j], acc[r][j]);
#pragma unroll
    for (int r = 0; r < 6; ++r) ld4<BF>(wsel, (wrow0 + 6 + r) * 128 + i, wv[r]);
#pragma unroll
    for (int r = 0; r < 6; ++r)
#pragma unroll
      for (int ci = 0; ci < 4; ++ci)
#pragma unroll
        for (int j = 0; j < 4; ++j)
          acc[6 + r][j] = fmaf(wv[r][ci], xv[ci][j], acc[6 + r][j]);
  }

  // ---- write f half only; v half stays in registers through B1 ----
  if (is_f) {
#pragma unroll
    for (int r = 0; r < 12; ++r)
#pragma unroll
      for (int j = 0; j < 4; ++j)
        sm.fh[(ty * 12 + r) * 65 + tx * 4 + j] = acc[r][j] + bias[r];
  }
  __syncthreads();

  // ---- phase B1: sim / sigmoid / argmax, stage (s, idx) into d_out ch 0..7 ----
  {
    float dm[4] = {0.f, 0.f, 0.f, 0.f};
    float n2 = 0.f;
#pragma unroll
    for (int c = 0; c < 24; ++c) {
      const float fc = sm.fh[(e * 24 + c) * 65 + tok];
      n2 += fc * fc;
      dm[0] += fc * sm.cn[0][c];
      dm[1] += fc * sm.cn[1][c];
      dm[2] += fc * sm.cn[2][c];
      dm[3] += fc * sm.cn[3][c];
    }
    const float inv = 1.f / fmaxf(sqrtf(n2), 1e-12f);
    float s[4];
#pragma unroll
    for (int m = 0; m < 4; ++m) {
      const float z = beta + alpha * dm[m] * inv;
      s[m] = 1.f / (1.f + __expf(-z));
    }
    float best = -1.f;
    int bi = 0;
#pragma unroll
    for (int m = 0; m < 4; ++m)
      if (s[m] > best) { best = s[m]; bi = m; }   // strict >: first max, like jnp.argmax

    const int hw = hw0 + tok;
    st1<BF>(out0, ((size_t)(b * 128 + e)) * kHW + hw, best);          // stage s
    st1<BF>(out0, ((size_t)(b * 128 + 4 + e)) * kHW + hw, (float)bi); // stage idx
    sm.s[e][tok]   = best;
    sm.idx[e][tok] = (unsigned char)bi;
    if (e == 0) {
      const int h = hw / kW;
      const int w = hw - h * kW;
      sm.q[tok] = (unsigned char)((h >= 56 ? 2 : 0) + (w >= 56 ? 1 : 0));
    }
  }
  __syncthreads();

  // ---- overwrite LDS with v half (from registers) ----
  if (!is_f) {
#pragma unroll
    for (int r = 0; r < 12; ++r)
#pragma unroll
      for (int j = 0; j < 4; ++j)
        sm.fh[((ty - 8) * 12 + r) * 65 + tx * 4 + j] = acc[r][j] + bias[r];
  }
  __syncthreads();

  // ---- phase B2: block reduction over 64 tokens, 2 token-halves in parallel ----
  float agg_m[4]  = {0.f, 0.f, 0.f, 0.f};
  float pool_q[4] = {0.f, 0.f, 0.f, 0.f};
  float cacc = 0.f;
  if (tid < 192) {
    const int half = tid / 96;
    const int c    = tid - half * 96;
    const int eh   = c / 24;
    const int row0 = c * 65;
    const int t20  = half * 32;
    for (int k = 0; k < 32; ++k) {
      const int t2 = t20 + k;
      const float v = sm.fh[row0 + t2];
      const float s = sm.s[eh][t2];
      const int  mi = sm.idx[eh][t2];
      const int  q  = sm.q[t2];
      const float sv = s * v;
      agg_m[0]  += (mi == 0) ? sv : 0.f;
      agg_m[1]  += (mi == 1) ? sv : 0.f;
      agg_m[2]  += (mi == 2) ? sv : 0.f;
      agg_m[3]  += (mi == 3) ? sv : 0.f;
      pool_q[0] += (q == 0) ? v : 0.f;
      pool_q[1] += (q == 1) ? v : 0.f;
      pool_q[2] += (q == 2) ? v : 0.f;
      pool_q[3] += (q == 3) ? v : 0.f;
    }
    const int cc  = c % 24;
    const int bh  = b * 4 + eh;
#pragma unroll
    for (int m = 0; m < 4; ++m) {
      atomicAdd(&aggsum[(bh * 4 + m) * 24 + cc], agg_m[m]);
      atomicAdd(&vpool[(bh * 4 + m) * 24 + cc], pool_q[m]);
    }
  } else if (tid < 224) {
    const int p  = tid - 192;
    const int em = p >> 1;
    const int ce = em >> 2, cm = em & 3;
    const int t20 = (p & 1) * 32;
    for (int k = 0; k < 32; ++k) {
      const int t2 = t20 + k;
      cacc += (sm.idx[ce][t2] == cm) ? sm.s[ce][t2] : 0.f;
    }
    atomicAdd(&cnt[b * 16 + em], cacc);
  }
}

__global__ __launch_bounds__(256, 4) void cluster_main(
    const int* __restrict__ flag,
    const void* x, const void* f_w, const void* f_b, const void* v_w, const void* v_b,
    const void* sim_alpha, const void* sim_beta, const void* centers,
    void* out0, float* aggsum, float* vpool, float* cnt)
{
  __shared__ SMain sm;
  if (*flag)
    main_body<true>(sm, x, f_w, f_b, v_w, v_b, sim_alpha, sim_beta, centers, out0, aggsum, vpool, cnt);
  else
    main_body<false>(sm, x, f_w, f_b, v_w, v_b, sim_alpha, sim_beta, centers, out0, aggsum, vpool, cnt);
}

// ---------------------------------------------------------------------------
// Kernel 2: finalize + proto-projection table.
//   aggf[em][c] = (aggsum + vpool/3136) / (cnt + 1)      (in LDS)
//   ptab[b][o*16 + e*4 + m] = sum_c proj_w[o][e*24+c] * aggf[e][m][c]
// Since s commutes with the c-sum, the per-token combine+proj GEMM collapses
// to 4 scaled lookups of ptab columns (kernel 3).
// ---------------------------------------------------------------------------
template <bool BF>
__device__ __forceinline__ void ptab_body(
    float* __restrict__ af, const void* __restrict__ proj_w,
    const float* __restrict__ aggsum, const float* __restrict__ vpool,
    const float* __restrict__ cnt, float* __restrict__ ptab)
{
  const int b   = blockIdx.x;
  const int tid = threadIdx.x;
  for (int k = tid; k < 384; k += 256) {
    const int em = k / 24;
    af[k] = (aggsum[b * 384 + k] + vpool[b * 384 + k] * (1.f / 3136.f)) / (cnt[b * 16 + em] + 1.f);
  }
  __syncthreads();
#pragma unroll
  for (int i = 0; i < 8; ++i) {
    const int g  = i * 256 + tid;      // g = o*16 + em
    const int o  = g >> 4;
    const int em = g & 15;
    const int e  = em >> 2;
    float acc = 0.f;
#pragma unroll
    for (int c = 0; c < 24; ++c)
      acc = fmaf(ld1<BF>(proj_w, (size_t)o * 96 + e * 24 + c), af[em * 24 + c], acc);
    ptab[b * 2048 + g] = acc;
  }
}

__global__ void cluster_ptab(const int* __restrict__ flag, const void* proj_w,
                             const float* __restrict__ aggsum, const float* __restrict__ vpool,
                             const float* __restrict__ cnt, float* __restrict__ ptab) {
  __shared__ float af[384];
  if (*flag) ptab_body<true>(af, proj_w, aggsum, vpool, cnt, ptab);
  else       ptab_body<false>(af, proj_w, aggsum, vpool, cnt, ptab);
}

// ---------------------------------------------------------------------------
// Kernel 3: out[o][token] = proj_b[o] + sum_e s_e(token) * ptab[b][o][e][idx_e]
// Memory-bound: ~103 MB write. Also emits the assignment map for b=0 (raw
// copy of the staged idx BEFORE the channel writes overwrite it).
// ---------------------------------------------------------------------------
struct SOut {
  float p[2048];   // [o][e*4+m] layout: conflict-free (m spreads banks)
  float pb[128];
};

template <bool BF>
__device__ __forceinline__ void out_body(
    SOut& so, const float* __restrict__ ptab,
    const void* __restrict__ proj_b, void* __restrict__ out0)
{
  const int tid = threadIdx.x;
  const int b   = blockIdx.x / kGrps;
  const int grp = blockIdx.x % kGrps;
  const int hw  = grp * 256 + tid;

  for (int k = tid; k < 2048; k += 256) so.p[k] = ptab[b * 2048 + k];
  if (tid < 128) so.pb[tid] = ld1<BF>(proj_b, tid);
  __syncthreads();

  const size_t base = ((size_t)(b * 128)) * kHW + hw;
  float sv[4];
  int   mi[4];
  float iv0 = 0.f;
#pragma unroll
  for (int e = 0; e < 4; ++e) {
    sv[e] = ld1<BF>(out0, base + (size_t)e * kHW);
    const float iv = ld1<BF>(out0, base + (size_t)(4 + e) * kHW);
    if (e == 0) iv0 = iv;
    mi[e] = (int)(iv + 0.5f);
  }
  if (b == 0) {
    // assignment map: head-0 idx of batch 0 (exact small-int in both dtypes)
    st1<BF>(out0, kOut1Off + hw, iv0);
  }

#pragma unroll 4
  for (int o = 0; o < 128; ++o) {
    float a = so.pb[o];
    a = fmaf(sv[0], so.p[o * 16 +  0 + mi[0]], a);
    a = fmaf(sv[1], so.p[o * 16 +  4 + mi[1]], a);
    a = fmaf(sv[2], so.p[o * 16 +  8 + mi[2]], a);
    a = fmaf(sv[3], so.p[o * 16 + 12 + mi[3]], a);
    st1<BF>(out0, base + (size_t)o * kHW, a);
  }
}

__global__ __launch_bounds__(256) void cluster_out(
    const int* __restrict__ flag,
    const void* proj_b, const float* __restrict__ ptab, void* out0)
{
  __shared__ SOut so;
  if (*flag) out_body<true>(so, ptab, proj_b, out0);
  else       out_body<false>(so, ptab, proj_b, out0);
}

}  // namespace

extern "C" void kernel_launch(void* const* d_in, const int* in_sizes, int n_in,
                              void* d_out, int out_size, void* d_ws, size_t ws_size,
                              hipStream_t stream) {
  const void* x         = d_in[0];
  const void* f_w       = d_in[1];
  const void* f_b       = d_in[2];
  const void* v_w       = d_in[3];
  const void* v_b       = d_in[4];
  const void* proj_w    = d_in[5];
  const void* proj_b    = d_in[6];
  const void* sim_alpha = d_in[7];
  const void* sim_beta  = d_in[8];
  const void* centers   = d_in[9];

  // ws layout: [0..15] bytes: dtype flag (int). Then floats:
  //   aggsum[6144] vpool[6144] cnt[256] ptab[32768]  -> ~177 KB total
  int*   flag   = (int*)d_ws;
  float* fws    = (float*)((char*)d_ws + 16);
  float* aggsum = fws;
  float* vpool  = fws + 6144;
  float* cnt    = fws + 12288;
  float* ptab   = fws + 12544;

  // zero flag + accumulators (ws is poisoned 0xAA before every call);
  // ptab is fully overwritten, no zeroing needed.
  hipMemsetAsync(d_ws, 0, 16 + 12544 * sizeof(float), stream);

  detect_dtype<<<dim3(1), dim3(256), 0, stream>>>((const unsigned short*)f_w, flag);
  cluster_main<<<dim3(16 * kTiles), dim3(256), 0, stream>>>(
      flag, x, f_w, f_b, v_w, v_b, sim_alpha, sim_beta, centers,
      d_out, aggsum, vpool, cnt);
  cluster_ptab<<<dim3(16), dim3(256), 0, stream>>>(flag, proj_w, aggsum, vpool, cnt, ptab);
  cluster_out<<<dim3(16 * kGrps), dim3(256), 0, stream>>>(flag, proj_b, ptab, d_out);
}

// Round 4
// 481.916 us; speedup vs baseline: 1.7053x; 1.0239x over previous
//
#include <hip/hip_runtime.h>
#include <hip/hip_bf16.h>

namespace {

constexpr int kCin   = 128;
constexpr int kHW    = 12544;   // 112*112
constexpr int kW     = 112;
constexpr int kGrps  = 49;      // output kernel: 49 blocks * 256 tokens per image
constexpr int kTiles = 196;     // main kernel: 196 blocks * 64 tokens per image
constexpr size_t kOut1Off = (size_t)16 * 128 * kHW;  // element offset of assignment map

__device__ __forceinline__ float bf2f(unsigned short u) {
  union { unsigned int i; float f; } v;
  v.i = ((unsigned int)u) << 16;
  return v.f;
}

__device__ __forceinline__ unsigned short f2bf(float f) {
  union { float f; unsigned int i; } v;
  v.f = f;
  unsigned int x = v.i;
  x += 0x7fffu + ((x >> 16) & 1u);   // RNE
  return (unsigned short)(x >> 16);
}

// ---- dtype-templated load/store helpers (BF=true: bf16, else fp32) ----
template <bool BF>
__device__ __forceinline__ float ld1(const void* p, size_t i) {
  if constexpr (BF) return bf2f(((const unsigned short*)p)[i]);
  else              return ((const float*)p)[i];
}
template <bool BF>
__device__ __forceinline__ void ld4(const void* p, size_t i, float o[4]) {
  if constexpr (BF) {
    const ushort4 u = *reinterpret_cast<const ushort4*>((const unsigned short*)p + i);
    o[0] = bf2f(u.x); o[1] = bf2f(u.y); o[2] = bf2f(u.z); o[3] = bf2f(u.w);
  } else {
    const float4 u = *reinterpret_cast<const float4*>((const float*)p + i);
    o[0] = u.x; o[1] = u.y; o[2] = u.z; o[3] = u.w;
  }
}
template <bool BF>
__device__ __forceinline__ void st1(void* p, size_t i, float v) {
  if constexpr (BF) ((unsigned short*)p)[i] = f2bf(v);
  else              ((float*)p)[i] = v;
}

// ---------------------------------------------------------------------------
// Kernel 0: detect input dtype. bf16 f_w values are ~N(0, 0.09): none exceed 4.
// fp32 f_w read as bf16 pairs: ~25% of ushorts are mantissa garbage with
// uniform-random exponent -> |v|>4 for ~half of those. flag=1 means bf16.
// ---------------------------------------------------------------------------
__global__ void detect_dtype(const unsigned short* __restrict__ fw, int* __restrict__ flag) {
  __shared__ int cnt_s;
  if (threadIdx.x == 0) cnt_s = 0;
  __syncthreads();
  int c = 0;
  for (int i = threadIdx.x; i < 4096; i += 256) {
    const float v = bf2f(fw[i]);
    if (fabsf(v) > 4.0f) ++c;
  }
  atomicAdd(&cnt_s, c);
  __syncthreads();
  if (threadIdx.x == 0) flag[0] = (cnt_s > 100) ? 0 : 1;
}

// ---------------------------------------------------------------------------
// Kernel 1: ONE 64-token tile per block (grid 16*196=3136). Phase A is now an
// LDS-staged GEMM: W[192][32-ch chunk] + X[32][64] staged cooperatively, FMAs
// fed by ds_read_b128. This cuts VMEM instrs 512 -> 32 per thread and kills
// the 16x L1 redundancy that pinned the VMEM pipe at ~340us across occupancy
// 16->39% (duration was occupancy-invariant => throughput-saturated pipe).
// W LDS rows padded to 36 floats (144B: 16B-aligned, worst bank aliasing
// 2-way = free). Stage region overlaid with fh via union (phase A scratch
// dead before fh is written; barrier-ordered).
// ---------------------------------------------------------------------------
struct alignas(16) SMain {
  union {
    struct {
      float w[192 * 36];     // 27648 B, padded stride 36
      float x[32 * 64];      // 8192 B
    } a;
    float fh[96 * 65];       // 24960 B: f rows (B1), then reused for v rows (B2)
  } u;
  float cn[4][24];
  float s[4][64];
  unsigned char idx[4][64];
  unsigned char q[64];
};

template <bool BF>
__device__ __forceinline__ void main_body(
    SMain& sm,
    const void* __restrict__ x,  const void* __restrict__ f_w, const void* __restrict__ f_b,
    const void* __restrict__ v_w, const void* __restrict__ v_b,
    const void* __restrict__ sim_alpha, const void* __restrict__ sim_beta,
    const void* __restrict__ centers,
    void* __restrict__ out0,
    float* __restrict__ aggsum, float* __restrict__ vpool, float* __restrict__ cnt)
{
  const int tid  = threadIdx.x;
  const int b    = blockIdx.x / kTiles;
  const int tile = blockIdx.x % kTiles;
  const int hw0  = tile * 64;

  if (tid < 4) {
    float cv[24];
    float n2 = 0.f;
#pragma unroll
    for (int c = 0; c < 24; ++c) { cv[c] = ld1<BF>(centers, tid * 24 + c); n2 += cv[c] * cv[c]; }
    const float inv = 1.f / fmaxf(sqrtf(n2), 1e-12f);
#pragma unroll
    for (int c = 0; c < 24; ++c) sm.cn[tid][c] = cv[c] * inv;
  }
  const float alpha = ld1<BF>(sim_alpha, 0);
  const float beta  = ld1<BF>(sim_beta, 0);

  // GEMM mapping: 16x16 threads; rows ty*12..+11 (0..191 across f;v), cols tx*4..+3
  const int ty = tid >> 4;
  const int tx = tid & 15;
  const bool is_f = (ty < 8);
  const void*  bsel  = is_f ? f_b : v_b;
  const size_t wrow0 = (size_t)(is_f ? ty * 12 : ty * 12 - 96);
  float bias[12];
#pragma unroll
  for (int r = 0; r < 12; ++r) bias[r] = ld1<BF>(bsel, wrow0 + r);

  const int e     = tid >> 6;
  const int tok   = tid & 63;
  const int lrow0 = ty * 12;       // LDS weight-row base (f rows 0..95, v rows 96..191)

  float acc[12][4];
#pragma unroll
  for (int r = 0; r < 12; ++r)
#pragma unroll
    for (int j = 0; j < 4; ++j) acc[r][j] = 0.f;

  // ---- phase A: LDS-staged [f;v](192) x tokens(64), 4 chunks of 32 channels ----
  for (int c0 = 0; c0 < 128; c0 += 32) {
    // stage W[0:192][c0:c0+32] -> sm.u.a.w (row-padded to 36 floats)
#pragma unroll
    for (int s = 0; s < 6; ++s) {
      const int u2  = tid + 256 * s;     // 0..1535: 192 rows x 8 col-groups
      const int row = u2 >> 3;
      const int cg  = u2 & 7;
      float t4[4];
      if (row < 96) ld4<BF>(f_w, (size_t)row * 128 + c0 + cg * 4, t4);
      else          ld4<BF>(v_w, (size_t)(row - 96) * 128 + c0 + cg * 4, t4);
      *reinterpret_cast<float4*>(&sm.u.a.w[row * 36 + cg * 4]) =
          make_float4(t4[0], t4[1], t4[2], t4[3]);
    }
    // stage X[c0:c0+32][64 tokens] -> sm.u.a.x
#pragma unroll
    for (int s = 0; s < 2; ++s) {
      const int u2 = tid + 256 * s;      // 0..511: 32 ch x 16 tok-groups
      const int ch = u2 >> 4;
      const int tg = u2 & 15;
      float t4[4];
      ld4<BF>(x, ((size_t)b * kCin + c0 + ch) * kHW + hw0 + tg * 4, t4);
      *reinterpret_cast<float4*>(&sm.u.a.x[ch * 64 + tg * 4]) =
          make_float4(t4[0], t4[1], t4[2], t4[3]);
    }
    __syncthreads();

    // compute on the chunk (same FMA order as un-staged version: k ascending)
#pragma unroll
    for (int kk = 0; kk < 32; kk += 4) {
      float xr[4][4];
#pragma unroll
      for (int ci = 0; ci < 4; ++ci) {
        const float4 v4 = *reinterpret_cast<const float4*>(&sm.u.a.x[(kk + ci) * 64 + tx * 4]);
        xr[ci][0] = v4.x; xr[ci][1] = v4.y; xr[ci][2] = v4.z; xr[ci][3] = v4.w;
      }
      float wr[6][4];
#pragma unroll
      for (int r = 0; r < 6; ++r) {
        const float4 v4 = *reinterpret_cast<const float4*>(&sm.u.a.w[(lrow0 + r) * 36 + kk]);
        wr[r][0] = v4.x; wr[r][1] = v4.y; wr[r][2] = v4.z; wr[r][3] = v4.w;
      }
#pragma unroll
      for (int r = 0; r < 6; ++r)
#pragma unroll
        for (int ci = 0; ci < 4; ++ci)
#pragma unroll
          for (int j = 0; j < 4; ++j)
            acc[r][j] = fmaf(wr[r][ci], xr[ci][j], acc[r][j]);
#pragma unroll
      for (int r = 0; r < 6; ++r) {
        const float4 v4 = *reinterpret_cast<const float4*>(&sm.u.a.w[(lrow0 + 6 + r) * 36 + kk]);
        wr[r][0] = v4.x; wr[r][1] = v4.y; wr[r][2] = v4.z; wr[r][3] = v4.w;
      }
#pragma unroll
      for (int r = 0; r < 6; ++r)
#pragma unroll
        for (int ci = 0; ci < 4; ++ci)
#pragma unroll
          for (int j = 0; j < 4; ++j)
            acc[6 + r][j] = fmaf(wr[r][ci], xr[ci][j], acc[6 + r][j]);
    }
    __syncthreads();   // stage region reusable (next chunk / fh overlay)
  }

  // ---- write f half into fh (overlays stage region; safe after loop-end sync) ----
  if (is_f) {
#pragma unroll
    for (int r = 0; r < 12; ++r)
#pragma unroll
      for (int j = 0; j < 4; ++j)
        sm.u.fh[(ty * 12 + r) * 65 + tx * 4 + j] = acc[r][j] + bias[r];
  }
  __syncthreads();

  // ---- phase B1: sim / sigmoid / argmax, stage (s, idx) into d_out ch 0..7 ----
  {
    float dm[4] = {0.f, 0.f, 0.f, 0.f};
    float n2 = 0.f;
#pragma unroll
    for (int c = 0; c < 24; ++c) {
      const float fc = sm.u.fh[(e * 24 + c) * 65 + tok];
      n2 += fc * fc;
      dm[0] += fc * sm.cn[0][c];
      dm[1] += fc * sm.cn[1][c];
      dm[2] += fc * sm.cn[2][c];
      dm[3] += fc * sm.cn[3][c];
    }
    const float inv = 1.f / fmaxf(sqrtf(n2), 1e-12f);
    float s[4];
#pragma unroll
    for (int m = 0; m < 4; ++m) {
      const float z = beta + alpha * dm[m] * inv;
      s[m] = 1.f / (1.f + __expf(-z));
    }
    float best = -1.f;
    int bi = 0;
#pragma unroll
    for (int m = 0; m < 4; ++m)
      if (s[m] > best) { best = s[m]; bi = m; }   // strict >: first max, like jnp.argmax

    const int hw = hw0 + tok;
    st1<BF>(out0, ((size_t)(b * 128 + e)) * kHW + hw, best);          // stage s
    st1<BF>(out0, ((size_t)(b * 128 + 4 + e)) * kHW + hw, (float)bi); // stage idx
    sm.s[e][tok]   = best;
    sm.idx[e][tok] = (unsigned char)bi;
    if (e == 0) {
      const int h = hw / kW;
      const int w = hw - h * kW;
      sm.q[tok] = (unsigned char)((h >= 56 ? 2 : 0) + (w >= 56 ? 1 : 0));
    }
  }
  __syncthreads();

  // ---- overwrite fh with v half (from registers) ----
  if (!is_f) {
#pragma unroll
    for (int r = 0; r < 12; ++r)
#pragma unroll
      for (int j = 0; j < 4; ++j)
        sm.u.fh[((ty - 8) * 12 + r) * 65 + tx * 4 + j] = acc[r][j] + bias[r];
  }
  __syncthreads();

  // ---- phase B2: block reduction over 64 tokens, 2 token-halves in parallel ----
  float agg_m[4]  = {0.f, 0.f, 0.f, 0.f};
  float pool_q[4] = {0.f, 0.f, 0.f, 0.f};
  float cacc = 0.f;
  if (tid < 192) {
    const int half = tid / 96;
    const int c    = tid - half * 96;
    const int eh   = c / 24;
    const int row0 = c * 65;
    const int t20  = half * 32;
    for (int k = 0; k < 32; ++k) {
      const int t2 = t20 + k;
      const float v = sm.u.fh[row0 + t2];
      const float s = sm.s[eh][t2];
      const int  mi = sm.idx[eh][t2];
      const int  q  = sm.q[t2];
      const float sv = s * v;
      agg_m[0]  += (mi == 0) ? sv : 0.f;
      agg_m[1]  += (mi == 1) ? sv : 0.f;
      agg_m[2]  += (mi == 2) ? sv : 0.f;
      agg_m[3]  += (mi == 3) ? sv : 0.f;
      pool_q[0] += (q == 0) ? v : 0.f;
      pool_q[1] += (q == 1) ? v : 0.f;
      pool_q[2] += (q == 2) ? v : 0.f;
      pool_q[3] += (q == 3) ? v : 0.f;
    }
    const int cc  = c % 24;
    const int bh  = b * 4 + eh;
#pragma unroll
    for (int m = 0; m < 4; ++m) {
      atomicAdd(&aggsum[(bh * 4 + m) * 24 + cc], agg_m[m]);
      atomicAdd(&vpool[(bh * 4 + m) * 24 + cc], pool_q[m]);
    }
  } else if (tid < 224) {
    const int p  = tid - 192;
    const int em = p >> 1;
    const int ce = em >> 2, cm = em & 3;
    const int t20 = (p & 1) * 32;
    for (int k = 0; k < 32; ++k) {
      const int t2 = t20 + k;
      cacc += (sm.idx[ce][t2] == cm) ? sm.s[ce][t2] : 0.f;
    }
    atomicAdd(&cnt[b * 16 + em], cacc);
  }
}

__global__ __launch_bounds__(256, 4) void cluster_main(
    const int* __restrict__ flag,
    const void* x, const void* f_w, const void* f_b, const void* v_w, const void* v_b,
    const void* sim_alpha, const void* sim_beta, const void* centers,
    void* out0, float* aggsum, float* vpool, float* cnt)
{
  __shared__ SMain sm;
  if (*flag)
    main_body<true>(sm, x, f_w, f_b, v_w, v_b, sim_alpha, sim_beta, centers, out0, aggsum, vpool, cnt);
  else
    main_body<false>(sm, x, f_w, f_b, v_w, v_b, sim_alpha, sim_beta, centers, out0, aggsum, vpool, cnt);
}

// ---------------------------------------------------------------------------
// Kernel 2: finalize + proto-projection table.
//   aggf[em][c] = (aggsum + vpool/3136) / (cnt + 1)      (in LDS)
//   ptab[b][o*16 + e*4 + m] = sum_c proj_w[o][e*24+c] * aggf[e][m][c]
// Since s commutes with the c-sum, the per-token combine+proj GEMM collapses
// to 4 scaled lookups of ptab columns (kernel 3).
// ---------------------------------------------------------------------------
template <bool BF>
__device__ __forceinline__ void ptab_body(
    float* __restrict__ af, const void* __restrict__ proj_w,
    const float* __restrict__ aggsum, const float* __restrict__ vpool,
    const float* __restrict__ cnt, float* __restrict__ ptab)
{
  const int b   = blockIdx.x;
  const int tid = threadIdx.x;
  for (int k = tid; k < 384; k += 256) {
    const int em = k / 24;
    af[k] = (aggsum[b * 384 + k] + vpool[b * 384 + k] * (1.f / 3136.f)) / (cnt[b * 16 + em] + 1.f);
  }
  __syncthreads();
#pragma unroll
  for (int i = 0; i < 8; ++i) {
    const int g  = i * 256 + tid;      // g = o*16 + em
    const int o  = g >> 4;
    const int em = g & 15;
    const int e  = em >> 2;
    float acc = 0.f;
#pragma unroll
    for (int c = 0; c < 24; ++c)
      acc = fmaf(ld1<BF>(proj_w, (size_t)o * 96 + e * 24 + c), af[em * 24 + c], acc);
    ptab[b * 2048 + g] = acc;
  }
}

__global__ void cluster_ptab(const int* __restrict__ flag, const void* proj_w,
                             const float* __restrict__ aggsum, const float* __restrict__ vpool,
                             const float* __restrict__ cnt, float* __restrict__ ptab) {
  __shared__ float af[384];
  if (*flag) ptab_body<true>(af, proj_w, aggsum, vpool, cnt, ptab);
  else       ptab_body<false>(af, proj_w, aggsum, vpool, cnt, ptab);
}

// ---------------------------------------------------------------------------
// Kernel 3: out[o][token] = proj_b[o] + sum_e s_e(token) * ptab[b][o][e][idx_e]
// Memory-bound: ~103 MB write. Also emits the assignment map for b=0 (raw
// copy of the staged idx BEFORE the channel writes overwrite it).
// ---------------------------------------------------------------------------
struct SOut {
  float p[2048];   // [o][e*4+m] layout: conflict-free (m spreads banks)
  float pb[128];
};

template <bool BF>
__device__ __forceinline__ void out_body(
    SOut& so, const float* __restrict__ ptab,
    const void* __restrict__ proj_b, void* __restrict__ out0)
{
  const int tid = threadIdx.x;
  const int b   = blockIdx.x / kGrps;
  const int grp = blockIdx.x % kGrps;
  const int hw  = grp * 256 + tid;

  for (int k = tid; k < 2048; k += 256) so.p[k] = ptab[b * 2048 + k];
  if (tid < 128) so.pb[tid] = ld1<BF>(proj_b, tid);
  __syncthreads();

  const size_t base = ((size_t)(b * 128)) * kHW + hw;
  float sv[4];
  int   mi[4];
  float iv0 = 0.f;
#pragma unroll
  for (int e = 0; e < 4; ++e) {
    sv[e] = ld1<BF>(out0, base + (size_t)e * kHW);
    const float iv = ld1<BF>(out0, base + (size_t)(4 + e) * kHW);
    if (e == 0) iv0 = iv;
    mi[e] = (int)(iv + 0.5f);
  }
  if (b == 0) {
    // assignment map: head-0 idx of batch 0 (exact small-int in both dtypes)
    st1<BF>(out0, kOut1Off + hw, iv0);
  }

#pragma unroll 4
  for (int o = 0; o < 128; ++o) {
    float a = so.pb[o];
    a = fmaf(sv[0], so.p[o * 16 +  0 + mi[0]], a);
    a = fmaf(sv[1], so.p[o * 16 +  4 + mi[1]], a);
    a = fmaf(sv[2], so.p[o * 16 +  8 + mi[2]], a);
    a = fmaf(sv[3], so.p[o * 16 + 12 + mi[3]], a);
    st1<BF>(out0, base + (size_t)o * kHW, a);
  }
}

__global__ __launch_bounds__(256) void cluster_out(
    const int* __restrict__ flag,
    const void* proj_b, const float* __restrict__ ptab, void* out0)
{
  __shared__ SOut so;
  if (*flag) out_body<true>(so, ptab, proj_b, out0);
  else       out_body<false>(so, ptab, proj_b, out0);
}

}  // namespace

extern "C" void kernel_launch(void* const* d_in, const int* in_sizes, int n_in,
                              void* d_out, int out_size, void* d_ws, size_t ws_size,
                              hipStream_t stream) {
  const void* x         = d_in[0];
  const void* f_w       = d_in[1];
  const void* f_b       = d_in[2];
  const void* v_w       = d_in[3];
  const void* v_b       = d_in[4];
  const void* proj_w    = d_in[5];
  const void* proj_b    = d_in[6];
  const void* sim_alpha = d_in[7];
  const void* sim_beta  = d_in[8];
  const void* centers   = d_in[9];

  // ws layout: [0..15] bytes: dtype flag (int). Then floats:
  //   aggsum[6144] vpool[6144] cnt[256] ptab[32768]  -> ~177 KB total
  int*   flag   = (int*)d_ws;
  float* fws    = (float*)((char*)d_ws + 16);
  float* aggsum = fws;
  float* vpool  = fws + 6144;
  float* cnt    = fws + 12288;
  float* ptab   = fws + 12544;

  // zero flag + accumulators (ws is poisoned 0xAA before every call);
  // ptab is fully overwritten, no zeroing needed.
  hipMemsetAsync(d_ws, 0, 16 + 12544 * sizeof(float), stream);

  detect_dtype<<<dim3(1), dim3(256), 0, stream>>>((const unsigned short*)f_w, flag);
  cluster_main<<<dim3(16 * kTiles), dim3(256), 0, stream>>>(
      flag, x, f_w, f_b, v_w, v_b, sim_alpha, sim_beta, centers,
      d_out, aggsum, vpool, cnt);
  cluster_ptab<<<dim3(16), dim3(256), 0, stream>>>(flag, proj_w, aggsum, vpool, cnt, ptab);
  cluster_out<<<dim3(16 * kGrps), dim3(256), 0, stream>>>(flag, proj_b, ptab, d_out);
}

// Round 5
// 428.735 us; speedup vs baseline: 1.9168x; 1.1240x over previous
//
#include <hip/hip_runtime.h>
#include <hip/hip_bf16.h>

namespace {

constexpr int kCin   = 128;
constexpr int kHW    = 12544;   // 112*112
constexpr int kW     = 112;
constexpr int kGrps  = 49;      // output kernel: 49 blocks * 256 tokens per image
constexpr int kTiles = 196;     // main kernel: 196 blocks * 64 tokens per image
constexpr size_t kOut1Off = (size_t)16 * 128 * kHW;  // element offset of assignment map

__device__ __forceinline__ float bf2f(unsigned short u) {
  union { unsigned int i; float f; } v;
  v.i = ((unsigned int)u) << 16;
  return v.f;
}

__device__ __forceinline__ unsigned short f2bf(float f) {
  union { float f; unsigned int i; } v;
  v.f = f;
  unsigned int x = v.i;
  x += 0x7fffu + ((x >> 16) & 1u);   // RNE
  return (unsigned short)(x >> 16);
}

// ---- dtype-templated load/store helpers (BF=true: bf16, else fp32) ----
template <bool BF>
__device__ __forceinline__ float ld1(const void* p, size_t i) {
  if constexpr (BF) return bf2f(((const unsigned short*)p)[i]);
  else              return ((const float*)p)[i];
}
template <bool BF>
__device__ __forceinline__ void ld4(const void* p, size_t i, float o[4]) {
  if constexpr (BF) {
    const ushort4 u = *reinterpret_cast<const ushort4*>((const unsigned short*)p + i);
    o[0] = bf2f(u.x); o[1] = bf2f(u.y); o[2] = bf2f(u.z); o[3] = bf2f(u.w);
  } else {
    const float4 u = *reinterpret_cast<const float4*>((const float*)p + i);
    o[0] = u.x; o[1] = u.y; o[2] = u.z; o[3] = u.w;
  }
}
template <bool BF>
__device__ __forceinline__ void st1(void* p, size_t i, float v) {
  if constexpr (BF) ((unsigned short*)p)[i] = f2bf(v);
  else              ((float*)p)[i] = v;
}

// ---------------------------------------------------------------------------
// Kernel 0: detect input dtype. bf16 f_w values are ~N(0, 0.09): none exceed 4.
// fp32 f_w read as bf16 pairs: ~25% of ushorts are mantissa garbage with
// uniform-random exponent -> |v|>4 for ~half of those. flag=1 means bf16.
// ---------------------------------------------------------------------------
__global__ void detect_dtype(const unsigned short* __restrict__ fw, int* __restrict__ flag) {
  __shared__ int cnt_s;
  if (threadIdx.x == 0) cnt_s = 0;
  __syncthreads();
  int c = 0;
  for (int i = threadIdx.x; i < 4096; i += 256) {
    const float v = bf2f(fw[i]);
    if (fabsf(v) > 4.0f) ++c;
  }
  atomicAdd(&cnt_s, c);
  __syncthreads();
  if (threadIdx.x == 0) flag[0] = (cnt_s > 100) ? 0 : 1;
}

// ---------------------------------------------------------------------------
// Kernel 1: ONE 64-token tile per block (grid 16*196=3136). Phase A is an
// LDS-staged GEMM: W[192][32-ch chunk] + X[32][64] staged cooperatively, FMAs
// fed by ds_read_b128 (VMEM 512 -> 32 ld4/thread, kills 16x L1 redundancy).
//
// __launch_bounds__(256, 2): with (256,4) the 128-VGPR cap was right at the
// staged loop's live set (acc48 + wr24 + xr16 + bias12 + staging temps) and
// the allocator spilled acc to scratch -> +200MB symmetric FETCH/WRITE and
// the kernel ran scratch-BW-bound at 1.4TB/s (494MB -> 353us, exact match;
// same 1.4TB/s ceiling as the R2 spill: 942MB -> 673us). LDS (37.9KB)
// already caps residency at 4 blocks/CU, so the 256-VGPR cap costs zero
// occupancy — and occupancy 16->39% was already shown duration-invariant.
// ---------------------------------------------------------------------------
struct alignas(16) SMain {
  union {
    struct {
      float w[192 * 36];     // 27648 B, padded stride 36 (144B: 16B-aligned, 2-way bank alias = free)
      float x[32 * 64];      // 8192 B
    } a;
    float fh[96 * 65];       // 24960 B: f rows (B1), then reused for v rows (B2)
  } u;
  float cn[4][24];
  float s[4][64];
  unsigned char idx[4][64];
  unsigned char q[64];
};

template <bool BF>
__device__ __forceinline__ void main_body(
    SMain& sm,
    const void* __restrict__ x,  const void* __restrict__ f_w, const void* __restrict__ f_b,
    const void* __restrict__ v_w, const void* __restrict__ v_b,
    const void* __restrict__ sim_alpha, const void* __restrict__ sim_beta,
    const void* __restrict__ centers,
    void* __restrict__ out0,
    float* __restrict__ aggsum, float* __restrict__ vpool, float* __restrict__ cnt)
{
  const int tid  = threadIdx.x;
  const int b    = blockIdx.x / kTiles;
  const int tile = blockIdx.x % kTiles;
  const int hw0  = tile * 64;

  if (tid < 4) {
    float cv[24];
    float n2 = 0.f;
#pragma unroll
    for (int c = 0; c < 24; ++c) { cv[c] = ld1<BF>(centers, tid * 24 + c); n2 += cv[c] * cv[c]; }
    const float inv = 1.f / fmaxf(sqrtf(n2), 1e-12f);
#pragma unroll
    for (int c = 0; c < 24; ++c) sm.cn[tid][c] = cv[c] * inv;
  }
  const float alpha = ld1<BF>(sim_alpha, 0);
  const float beta  = ld1<BF>(sim_beta, 0);

  // GEMM mapping: 16x16 threads; rows ty*12..+11 (0..191 across f;v), cols tx*4..+3
  const int ty = tid >> 4;
  const int tx = tid & 15;
  const bool is_f = (ty < 8);
  const void*  bsel  = is_f ? f_b : v_b;
  const size_t wrow0 = (size_t)(is_f ? ty * 12 : ty * 12 - 96);
  float bias[12];
#pragma unroll
  for (int r = 0; r < 12; ++r) bias[r] = ld1<BF>(bsel, wrow0 + r);

  const int e     = tid >> 6;
  const int tok   = tid & 63;
  const int lrow0 = ty * 12;       // LDS weight-row base (f rows 0..95, v rows 96..191)

  float acc[12][4];
#pragma unroll
  for (int r = 0; r < 12; ++r)
#pragma unroll
    for (int j = 0; j < 4; ++j) acc[r][j] = 0.f;

  // ---- phase A: LDS-staged [f;v](192) x tokens(64), 4 chunks of 32 channels ----
  for (int c0 = 0; c0 < 128; c0 += 32) {
    // stage W[0:192][c0:c0+32] -> sm.u.a.w (row-padded to 36 floats)
#pragma unroll
    for (int s = 0; s < 6; ++s) {
      const int u2  = tid + 256 * s;     // 0..1535: 192 rows x 8 col-groups
      const int row = u2 >> 3;
      const int cg  = u2 & 7;
      float t4[4];
      if (row < 96) ld4<BF>(f_w, (size_t)row * 128 + c0 + cg * 4, t4);
      else          ld4<BF>(v_w, (size_t)(row - 96) * 128 + c0 + cg * 4, t4);
      *reinterpret_cast<float4*>(&sm.u.a.w[row * 36 + cg * 4]) =
          make_float4(t4[0], t4[1], t4[2], t4[3]);
    }
    // stage X[c0:c0+32][64 tokens] -> sm.u.a.x
#pragma unroll
    for (int s = 0; s < 2; ++s) {
      const int u2 = tid + 256 * s;      // 0..511: 32 ch x 16 tok-groups
      const int ch = u2 >> 4;
      const int tg = u2 & 15;
      float t4[4];
      ld4<BF>(x, ((size_t)b * kCin + c0 + ch) * kHW + hw0 + tg * 4, t4);
      *reinterpret_cast<float4*>(&sm.u.a.x[ch * 64 + tg * 4]) =
          make_float4(t4[0], t4[1], t4[2], t4[3]);
    }
    __syncthreads();

    // compute on the chunk (same FMA order as un-staged version: k ascending)
#pragma unroll
    for (int kk = 0; kk < 32; kk += 4) {
      float xr[4][4];
#pragma unroll
      for (int ci = 0; ci < 4; ++ci) {
        const float4 v4 = *reinterpret_cast<const float4*>(&sm.u.a.x[(kk + ci) * 64 + tx * 4]);
        xr[ci][0] = v4.x; xr[ci][1] = v4.y; xr[ci][2] = v4.z; xr[ci][3] = v4.w;
      }
      float wr[6][4];
#pragma unroll
      for (int r = 0; r < 6; ++r) {
        const float4 v4 = *reinterpret_cast<const float4*>(&sm.u.a.w[(lrow0 + r) * 36 + kk]);
        wr[r][0] = v4.x; wr[r][1] = v4.y; wr[r][2] = v4.z; wr[r][3] = v4.w;
      }
#pragma unroll
      for (int r = 0; r < 6; ++r)
#pragma unroll
        for (int ci = 0; ci < 4; ++ci)
#pragma unroll
          for (int j = 0; j < 4; ++j)
            acc[r][j] = fmaf(wr[r][ci], xr[ci][j], acc[r][j]);
#pragma unroll
      for (int r = 0; r < 6; ++r) {
        const float4 v4 = *reinterpret_cast<const float4*>(&sm.u.a.w[(lrow0 + 6 + r) * 36 + kk]);
        wr[r][0] = v4.x; wr[r][1] = v4.y; wr[r][2] = v4.z; wr[r][3] = v4.w;
      }
#pragma unroll
      for (int r = 0; r < 6; ++r)
#pragma unroll
        for (int ci = 0; ci < 4; ++ci)
#pragma unroll
          for (int j = 0; j < 4; ++j)
            acc[6 + r][j] = fmaf(wr[r][ci], xr[ci][j], acc[6 + r][j]);
    }
    __syncthreads();   // stage region reusable (next chunk / fh overlay)
  }

  // ---- write f half into fh (overlays stage region; safe after loop-end sync) ----
  if (is_f) {
#pragma unroll
    for (int r = 0; r < 12; ++r)
#pragma unroll
      for (int j = 0; j < 4; ++j)
        sm.u.fh[(ty * 12 + r) * 65 + tx * 4 + j] = acc[r][j] + bias[r];
  }
  __syncthreads();

  // ---- phase B1: sim / sigmoid / argmax, stage (s, idx) into d_out ch 0..7 ----
  {
    float dm[4] = {0.f, 0.f, 0.f, 0.f};
    float n2 = 0.f;
#pragma unroll
    for (int c = 0; c < 24; ++c) {
      const float fc = sm.u.fh[(e * 24 + c) * 65 + tok];
      n2 += fc * fc;
      dm[0] += fc * sm.cn[0][c];
      dm[1] += fc * sm.cn[1][c];
      dm[2] += fc * sm.cn[2][c];
      dm[3] += fc * sm.cn[3][c];
    }
    const float inv = 1.f / fmaxf(sqrtf(n2), 1e-12f);
    float s[4];
#pragma unroll
    for (int m = 0; m < 4; ++m) {
      const float z = beta + alpha * dm[m] * inv;
      s[m] = 1.f / (1.f + __expf(-z));
    }
    float best = -1.f;
    int bi = 0;
#pragma unroll
    for (int m = 0; m < 4; ++m)
      if (s[m] > best) { best = s[m]; bi = m; }   // strict >: first max, like jnp.argmax

    const int hw = hw0 + tok;
    st1<BF>(out0, ((size_t)(b * 128 + e)) * kHW + hw, best);          // stage s
    st1<BF>(out0, ((size_t)(b * 128 + 4 + e)) * kHW + hw, (float)bi); // stage idx
    sm.s[e][tok]   = best;
    sm.idx[e][tok] = (unsigned char)bi;
    if (e == 0) {
      const int h = hw / kW;
      const int w = hw - h * kW;
      sm.q[tok] = (unsigned char)((h >= 56 ? 2 : 0) + (w >= 56 ? 1 : 0));
    }
  }
  __syncthreads();

  // ---- overwrite fh with v half (from registers) ----
  if (!is_f) {
#pragma unroll
    for (int r = 0; r < 12; ++r)
#pragma unroll
      for (int j = 0; j < 4; ++j)
        sm.u.fh[((ty - 8) * 12 + r) * 65 + tx * 4 + j] = acc[r][j] + bias[r];
  }
  __syncthreads();

  // ---- phase B2: block reduction over 64 tokens, 2 token-halves in parallel ----
  float agg_m[4]  = {0.f, 0.f, 0.f, 0.f};
  float pool_q[4] = {0.f, 0.f, 0.f, 0.f};
  float cacc = 0.f;
  if (tid < 192) {
    const int half = tid / 96;
    const int c    = tid - half * 96;
    const int eh   = c / 24;
    const int row0 = c * 65;
    const int t20  = half * 32;
    for (int k = 0; k < 32; ++k) {
      const int t2 = t20 + k;
      const float v = sm.u.fh[row0 + t2];
      const float s = sm.s[eh][t2];
      const int  mi = sm.idx[eh][t2];
      const int  q  = sm.q[t2];
      const float sv = s * v;
      agg_m[0]  += (mi == 0) ? sv : 0.f;
      agg_m[1]  += (mi == 1) ? sv : 0.f;
      agg_m[2]  += (mi == 2) ? sv : 0.f;
      agg_m[3]  += (mi == 3) ? sv : 0.f;
      pool_q[0] += (q == 0) ? v : 0.f;
      pool_q[1] += (q == 1) ? v : 0.f;
      pool_q[2] += (q == 2) ? v : 0.f;
      pool_q[3] += (q == 3) ? v : 0.f;
    }
    const int cc  = c % 24;
    const int bh  = b * 4 + eh;
#pragma unroll
    for (int m = 0; m < 4; ++m) {
      atomicAdd(&aggsum[(bh * 4 + m) * 24 + cc], agg_m[m]);
      atomicAdd(&vpool[(bh * 4 + m) * 24 + cc], pool_q[m]);
    }
  } else if (tid < 224) {
    const int p  = tid - 192;
    const int em = p >> 1;
    const int ce = em >> 2, cm = em & 3;
    const int t20 = (p & 1) * 32;
    for (int k = 0; k < 32; ++k) {
      const int t2 = t20 + k;
      cacc += (sm.idx[ce][t2] == cm) ? sm.s[ce][t2] : 0.f;
    }
    atomicAdd(&cnt[b * 16 + em], cacc);
  }
}

__global__ __launch_bounds__(256, 2) void cluster_main(
    const int* __restrict__ flag,
    const void* x, const void* f_w, const void* f_b, const void* v_w, const void* v_b,
    const void* sim_alpha, const void* sim_beta, const void* centers,
    void* out0, float* aggsum, float* vpool, float* cnt)
{
  __shared__ SMain sm;
  if (*flag)
    main_body<true>(sm, x, f_w, f_b, v_w, v_b, sim_alpha, sim_beta, centers, out0, aggsum, vpool, cnt);
  else
    main_body<false>(sm, x, f_w, f_b, v_w, v_b, sim_alpha, sim_beta, centers, out0, aggsum, vpool, cnt);
}

// ---------------------------------------------------------------------------
// Kernel 2: finalize + proto-projection table.
//   aggf[em][c] = (aggsum + vpool/3136) / (cnt + 1)      (in LDS)
//   ptab[b][o*16 + e*4 + m] = sum_c proj_w[o][e*24+c] * aggf[e][m][c]
// Since s commutes with the c-sum, the per-token combine+proj GEMM collapses
// to 4 scaled lookups of ptab columns (kernel 3).
// ---------------------------------------------------------------------------
template <bool BF>
__device__ __forceinline__ void ptab_body(
    float* __restrict__ af, const void* __restrict__ proj_w,
    const float* __restrict__ aggsum, const float* __restrict__ vpool,
    const float* __restrict__ cnt, float* __restrict__ ptab)
{
  const int b   = blockIdx.x;
  const int tid = threadIdx.x;
  for (int k = tid; k < 384; k += 256) {
    const int em = k / 24;
    af[k] = (aggsum[b * 384 + k] + vpool[b * 384 + k] * (1.f / 3136.f)) / (cnt[b * 16 + em] + 1.f);
  }
  __syncthreads();
#pragma unroll
  for (int i = 0; i < 8; ++i) {
    const int g  = i * 256 + tid;      // g = o*16 + em
    const int o  = g >> 4;
    const int em = g & 15;
    const int e  = em >> 2;
    float acc = 0.f;
#pragma unroll
    for (int c = 0; c < 24; ++c)
      acc = fmaf(ld1<BF>(proj_w, (size_t)o * 96 + e * 24 + c), af[em * 24 + c], acc);
    ptab[b * 2048 + g] = acc;
  }
}

__global__ void cluster_ptab(const int* __restrict__ flag, const void* proj_w,
                             const float* __restrict__ aggsum, const float* __restrict__ vpool,
                             const float* __restrict__ cnt, float* __restrict__ ptab) {
  __shared__ float af[384];
  if (*flag) ptab_body<true>(af, proj_w, aggsum, vpool, cnt, ptab);
  else       ptab_body<false>(af, proj_w, aggsum, vpool, cnt, ptab);
}

// ---------------------------------------------------------------------------
// Kernel 3: out[o][token] = proj_b[o] + sum_e s_e(token) * ptab[b][o][e][idx_e]
// Memory-bound: ~103 MB write. Also emits the assignment map for b=0 (raw
// copy of the staged idx BEFORE the channel writes overwrite it).
// ---------------------------------------------------------------------------
struct SOut {
  float p[2048];   // [o][e*4+m] layout: conflict-free (m spreads banks)
  float pb[128];
};

template <bool BF>
__device__ __forceinline__ void out_body(
    SOut& so, const float* __restrict__ ptab,
    const void* __restrict__ proj_b, void* __restrict__ out0)
{
  const int tid = threadIdx.x;
  const int b   = blockIdx.x / kGrps;
  const int grp = blockIdx.x % kGrps;
  const int hw  = grp * 256 + tid;

  for (int k = tid; k < 2048; k += 256) so.p[k] = ptab[b * 2048 + k];
  if (tid < 128) so.pb[tid] = ld1<BF>(proj_b, tid);
  __syncthreads();

  const size_t base = ((size_t)(b * 128)) * kHW + hw;
  float sv[4];
  int   mi[4];
  float iv0 = 0.f;
#pragma unroll
  for (int e = 0; e < 4; ++e) {
    sv[e] = ld1<BF>(out0, base + (size_t)e * kHW);
    const float iv = ld1<BF>(out0, base + (size_t)(4 + e) * kHW);
    if (e == 0) iv0 = iv;
    mi[e] = (int)(iv + 0.5f);
  }
  if (b == 0) {
    // assignment map: head-0 idx of batch 0 (exact small-int in both dtypes)
    st1<BF>(out0, kOut1Off + hw, iv0);
  }

#pragma unroll 4
  for (int o = 0; o < 128; ++o) {
    float a = so.pb[o];
    a = fmaf(sv[0], so.p[o * 16 +  0 + mi[0]], a);
    a = fmaf(sv[1], so.p[o * 16 +  4 + mi[1]], a);
    a = fmaf(sv[2], so.p[o * 16 +  8 + mi[2]], a);
    a = fmaf(sv[3], so.p[o * 16 + 12 + mi[3]], a);
    st1<BF>(out0, base + (size_t)o * kHW, a);
  }
}

__global__ __launch_bounds__(256) void cluster_out(
    const int* __restrict__ flag,
    const void* proj_b, const float* __restrict__ ptab, void* out0)
{
  __shared__ SOut so;
  if (*flag) out_body<true>(so, ptab, proj_b, out0);
  else       out_body<false>(so, ptab, proj_b, out0);
}

}  // namespace

extern "C" void kernel_launch(void* const* d_in, const int* in_sizes, int n_in,
                              void* d_out, int out_size, void* d_ws, size_t ws_size,
                              hipStream_t stream) {
  const void* x         = d_in[0];
  const void* f_w       = d_in[1];
  const void* f_b       = d_in[2];
  const void* v_w       = d_in[3];
  const void* v_b       = d_in[4];
  const void* proj_w    = d_in[5];
  const void* proj_b    = d_in[6];
  const void* sim_alpha = d_in[7];
  const void* sim_beta  = d_in[8];
  const void* centers   = d_in[9];

  // ws layout: [0..15] bytes: dtype flag (int). Then floats:
  //   aggsum[6144] vpool[6144] cnt[256] ptab[32768]  -> ~177 KB total
  int*   flag   = (int*)d_ws;
  float* fws    = (float*)((char*)d_ws + 16);
  float* aggsum = fws;
  float* vpool  = fws + 6144;
  float* cnt    = fws + 12288;
  float* ptab   = fws + 12544;

  // zero flag + accumulators (ws is poisoned 0xAA before every call);
  // ptab is fully overwritten, no zeroing needed.
  hipMemsetAsync(d_ws, 0, 16 + 12544 * sizeof(float), stream);

  detect_dtype<<<dim3(1), dim3(256), 0, stream>>>((const unsigned short*)f_w, flag);
  cluster_main<<<dim3(16 * kTiles), dim3(256), 0, stream>>>(
      flag, x, f_w, f_b, v_w, v_b, sim_alpha, sim_beta, centers,
      d_out, aggsum, vpool, cnt);
  cluster_ptab<<<dim3(16), dim3(256), 0, stream>>>(flag, proj_w, aggsum, vpool, cnt, ptab);
  cluster_out<<<dim3(16 * kGrps), dim3(256), 0, stream>>>(flag, proj_b, ptab, d_out);
}